// Round 3
// baseline (354.504 us; speedup 1.0000x reference)
//
#include <hip/hip_runtime.h>

// 4-bit ripple-borrow subtractor.
// A,B: (N,4) float32 in {0.0,1.0}. Out: [diffs (N,4) | borrow (N,1)] flat f32.
// Index 3 = LSB (reference loops i = 3..0).
//
// ILP=4: each thread handles rows {t, t+s, t+2s, t+3s} (s = total threads) so
// every load/store instruction stays perfectly lane-coalesced while the wave
// keeps 8 x 16B loads in flight. Output stores are nontemporal (native clang
// vector type required by the builtin): outputs are write-once; keeping them
// out of L2/L3 preserves Infinity-Cache residency for the 268 MB input set.

#define ILP 4

typedef float v4f __attribute__((ext_vector_type(4)));

__device__ __forceinline__ void sub4(const v4f a, const v4f b,
                                     v4f& r, float& bo)
{
    int a0 = (a.x != 0.0f), a1 = (a.y != 0.0f), a2 = (a.z != 0.0f), a3 = (a.w != 0.0f);
    int b0 = (b.x != 0.0f), b1 = (b.y != 0.0f), b2 = (b.z != 0.0f), b3 = (b.w != 0.0f);

    int bor, na;
    int d3 = a3 ^ b3;            na = a3 ^ 1; bor = (na & b3);                      // bor-in = 0
    int d2 = a2 ^ b2 ^ bor;      na = a2 ^ 1; bor = (na & b2) | ((na | b2) & bor);
    int d1 = a1 ^ b1 ^ bor;      na = a1 ^ 1; bor = (na & b1) | ((na | b1) & bor);
    int d0 = a0 ^ b0 ^ bor;      na = a0 ^ 1; bor = (na & b0) | ((na | b0) & bor);

    r.x = (float)d0; r.y = (float)d1; r.z = (float)d2; r.w = (float)d3;
    bo = (float)bor;
}

__global__ __launch_bounds__(256) void Subtractor4Bit_kernel(
    const v4f* __restrict__ A,
    const v4f* __restrict__ B,
    v4f* __restrict__ res,
    float* __restrict__ borrow_out,
    int n_rows)
{
    int tid    = blockIdx.x * blockDim.x + threadIdx.x;
    int stride = gridDim.x * blockDim.x;

    int idx[ILP];
    v4f a[ILP], b[ILP];
    bool valid[ILP];

#pragma unroll
    for (int k = 0; k < ILP; ++k) {
        idx[k]   = tid + k * stride;
        valid[k] = idx[k] < n_rows;
    }
    // Issue all loads first: 8 x 16B in flight per thread.
#pragma unroll
    for (int k = 0; k < ILP; ++k) if (valid[k]) a[k] = A[idx[k]];
#pragma unroll
    for (int k = 0; k < ILP; ++k) if (valid[k]) b[k] = B[idx[k]];

#pragma unroll
    for (int k = 0; k < ILP; ++k) {
        if (!valid[k]) continue;
        v4f r; float bo;
        sub4(a[k], b[k], r, bo);
        __builtin_nontemporal_store(r,  &res[idx[k]]);
        __builtin_nontemporal_store(bo, &borrow_out[idx[k]]);
    }
}

extern "C" void kernel_launch(void* const* d_in, const int* in_sizes, int n_in,
                              void* d_out, int out_size, void* d_ws, size_t ws_size,
                              hipStream_t stream)
{
    const v4f* A = (const v4f*)d_in[0];
    const v4f* B = (const v4f*)d_in[1];
    float* out = (float*)d_out;

    int n_rows = in_sizes[0] / 4;             // (N,4) -> N rows
    v4f* res = (v4f*)out;                     // first 4*N floats: diffs
    float* borrow = out + (size_t)n_rows * 4; // last N floats: borrow

    int block = 256;
    int per_block = block * ILP;
    int grid = (n_rows + per_block - 1) / per_block;
    Subtractor4Bit_kernel<<<grid, block, 0, stream>>>(A, B, res, borrow, n_rows);
}

// Round 4
// 332.221 us; speedup vs baseline: 1.0671x; 1.0671x over previous
//
#include <hip/hip_runtime.h>

// 4-bit ripple-borrow subtractor, one thread per row.
// A,B: (N,4) float32, values exactly {0.0f, 1.0f}. Index 3 = LSB.
// Out: [diffs (N,4) | borrow (N,1)] flat float32.
//
// Pure bitwise formulation: for x,y in {0x00000000, 0x3f800000},
//   XOR(x,y) = x^y, AND = x&y, OR = x|y, NOT = x^0x3f800000
// all stay in {0, 0x3f800000}, i.e. exactly 0.0f/1.0f — no compares,
// no int<->float converts, minimal dep chain from load to store.

typedef unsigned int u32;

__global__ __launch_bounds__(256) void Subtractor4Bit_kernel(
    const uint4* __restrict__ A,
    const uint4* __restrict__ B,
    uint4* __restrict__ res,
    u32* __restrict__ borrow_out,
    int n_rows)
{
    int i = blockIdx.x * blockDim.x + threadIdx.x;
    if (i >= n_rows) return;

    uint4 a = A[i];
    uint4 b = B[i];

    const u32 ONE = 0x3f800000u;

    u32 bor, na;
    // i = 3 (LSB), borrow-in = 0
    u32 d3 = a.w ^ b.w;        na = a.w ^ ONE; bor = na & b.w;
    // i = 2
    u32 d2 = a.z ^ b.z ^ bor;  na = a.z ^ ONE; bor = (na & b.z) | ((na | b.z) & bor);
    // i = 1
    u32 d1 = a.y ^ b.y ^ bor;  na = a.y ^ ONE; bor = (na & b.y) | ((na | b.y) & bor);
    // i = 0 (MSB)
    u32 d0 = a.x ^ b.x ^ bor;  na = a.x ^ ONE; bor = (na & b.x) | ((na | b.x) & bor);

    uint4 r; r.x = d0; r.y = d1; r.z = d2; r.w = d3;
    res[i] = r;
    borrow_out[i] = bor;
}

extern "C" void kernel_launch(void* const* d_in, const int* in_sizes, int n_in,
                              void* d_out, int out_size, void* d_ws, size_t ws_size,
                              hipStream_t stream)
{
    const uint4* A = (const uint4*)d_in[0];
    const uint4* B = (const uint4*)d_in[1];
    u32* out = (u32*)d_out;

    int n_rows = in_sizes[0] / 4;             // (N,4) -> N rows
    uint4* res = (uint4*)out;                 // first 4*N words: diffs
    u32* borrow = out + (size_t)n_rows * 4;   // last N words: borrow

    int block = 256;
    int grid = (n_rows + block - 1) / block;
    Subtractor4Bit_kernel<<<grid, block, 0, stream>>>(A, B, res, borrow, n_rows);
}